// Round 1
// baseline (3290.383 us; speedup 1.0000x reference)
//
#include <hip/hip_runtime.h>
#include <math.h>

// Problem constants (from reference)
#define LATENT 256
#define EMBD 128
#define VOCAB 600
#define NLEV 12
#define NNODES 65536
#define NTREES 32
#define GATES 1024           // 4*LATENT
#define NPB 4                // nodes per block (== waves per block for reductions)
#define MAXM 8192            // max nodes per level we support (actual ~5461)
#define INV_N (1.0f/65536.0f)

__device__ __forceinline__ float sigm(float x){ return 1.0f/(1.0f+expf(-x)); }
__device__ __forceinline__ float bcef(float x, float y){
  // numerically stable BCEWithLogits
  return fmaxf(x,0.0f) - x*y + log1pf(expf(-fabsf(x)));
}

__global__ void zero_kernel(float* loss, int* counts){
  int t = threadIdx.x;
  if (t==0) *loss = 0.0f;
  if (t<NLEV) counts[t]=0;
}

// dst[k*rows + r] = src[r*cols + k]
__global__ void transpose_kernel(const float* __restrict__ src, float* __restrict__ dst,
                                 int rows, int cols){
  int idx = blockIdx.x*blockDim.x + threadIdx.x;
  if (idx >= rows*cols) return;
  int r = idx/cols, k = idx - r*cols;
  dst[k*rows + r] = src[idx];
}

// root_h[b,t] = b_l2h[t] + sum_k z[b,k]*W_l2h[t,k]   (z @ W^T)
__global__ __launch_bounds__(LATENT) void root_kernel(const float* __restrict__ z,
    const float* __restrict__ W, const float* __restrict__ b, float* __restrict__ root_h){
  __shared__ float zs[LATENT];
  int bi = blockIdx.x; int t = threadIdx.x;
  zs[t] = z[bi*LATENT+t];
  __syncthreads();
  float acc = b[t];
  for (int k=0;k<LATENT;k++) acc += zs[k]*W[t*LATENT+k];
  root_h[bi*LATENT+t] = acc;
}

__global__ __launch_bounds__(LATENT) void init_kernel(const int* __restrict__ node_level,
    const int* __restrict__ tree_id, const float* __restrict__ root_h,
    float* __restrict__ h_state, float* __restrict__ c_state){
  int n = blockIdx.x; int t = threadIdx.x;
  int lvl = node_level[n];
  float h = 0.0f;
  if (lvl==0) h = root_h[tree_id[n]*LATENT + t];
  h_state[n*LATENT+t]=h;
  c_state[n*LATENT+t]=0.0f;
}

__global__ void build_lists_kernel(const int* __restrict__ node_level,
    int* __restrict__ counts, int* __restrict__ lists){
  int n = blockIdx.x*blockDim.x + threadIdx.x;
  if (n>=NNODES) return;
  int lvl = node_level[n];
  if (lvl>=1){
    int pos = atomicAdd(&counts[lvl],1);
    lists[lvl*NNODES + pos] = n;
  }
}

__global__ __launch_bounds__(256) void forward_kernel(
    int lvl,
    const int* __restrict__ lists, const int* __restrict__ counts,
    const float* __restrict__ h_state, const float* __restrict__ c_state,
    const float* __restrict__ emb_table, const int* __restrict__ features,
    const int* __restrict__ parent_idx, const int* __restrict__ sibling_idx,
    const int* __restrict__ has_prev,
    const int* __restrict__ is_parent, const int* __restrict__ has_sib_lbl,
    const int* __restrict__ is_res,
    const float* __restrict__ W_ph1, const float* __restrict__ b_ph1,
    const float* __restrict__ W_ph2, const float* __restrict__ b_ph2,
    const float* __restrict__ W_gate, const float* __restrict__ b_gate,
    const float* __restrict__ W_topo, const float* __restrict__ b_topo,
    const float* __restrict__ W_pred, const float* __restrict__ b_pred,
    const float* __restrict__ W_ihT, const float* __restrict__ W_hhT,
    const float* __restrict__ b_ih, const float* __restrict__ b_hh,
    float* __restrict__ tmp_h, float* __restrict__ tmp_c,
    float* __restrict__ loss_out)
{
  const int count = counts[lvl];
  const int base = blockIdx.x * NPB;
  if (base >= count) return;
  const int t = threadIdx.x;
  const int nvalid = min(NPB, count - base);

  __shared__ float sh_par[NPB][LATENT];
  __shared__ float sh_sib[NPB][LATENT];
  __shared__ float sh_pred[NPB][LATENT];
  __shared__ float sh_pu[NPB][LATENT];
  __shared__ float sh_emb[NPB][EMBD];
  __shared__ float sh_logits[NPB][VOCAB];
  __shared__ int sh_node[NPB];
  __shared__ int sh_feat[NPB];
  __shared__ int sh_pidx[NPB];

  if (t < NPB) {
    int j = t;
    int m = base + ((j < nvalid) ? j : 0);   // clamp: duplicate row, loss guarded below
    int node = lists[lvl*NNODES + m];
    sh_node[j] = node;
    sh_feat[j] = features[node];
    sh_pidx[j] = parent_idx[node];
  }
  __syncthreads();

  // gather parent/sibling h, embedding
  for (int j=0;j<NPB;j++){
    int node = sh_node[j];
    sh_par[j][t] = h_state[sh_pidx[j]*LATENT + t];
    float hs = 0.0f;
    if (has_prev[node] > 0) hs = h_state[sibling_idx[node]*LATENT + t];
    sh_sib[j][t] = hs;
    if (t < EMBD) sh_emb[j][t] = emb_table[sh_feat[j]*EMBD + t];
  }
  __syncthreads();

  // PredictiveHidden: tanh(h_par@W_ph1 + h_sib@W_ph2 + b) ; AddGate: h_par + sig(h_sib@W_gate+b)*h_sib
  {
    float accp[NPB], accg[NPB];
    #pragma unroll
    for (int j=0;j<NPB;j++){ accp[j]=0.f; accg[j]=0.f; }
    for (int k=0;k<LATENT;k++){
      float w1 = W_ph1[k*LATENT + t];
      float w2 = W_ph2[k*LATENT + t];
      float wg = W_gate[k*LATENT + t];
      #pragma unroll
      for (int j=0;j<NPB;j++){
        accp[j] += sh_par[j][k]*w1;
        accp[j] += sh_sib[j][k]*w2;
        accg[j] += sh_sib[j][k]*wg;
      }
    }
    float bp = b_ph1[t] + b_ph2[t];
    float bg = b_gate[t];
    #pragma unroll
    for (int j=0;j<NPB;j++){
      sh_pred[j][t] = tanhf(accp[j] + bp);
      sh_pu[j][t]   = sh_par[j][t] + sigm(accg[j]+bg)*sh_sib[j][t];
    }
  }
  __syncthreads();

  const int wv = t >> 6;
  const int lane = t & 63;

  // topo (3 logits) + BCE : wave wv handles node wv
  {
    int j = wv;
    float a0=0.f,a1=0.f,a2=0.f;
    for (int k=lane;k<LATENT;k+=64){
      float hp = sh_pred[j][k];
      a0 += hp*W_topo[k*3+0];
      a1 += hp*W_topo[k*3+1];
      a2 += hp*W_topo[k*3+2];
    }
    #pragma unroll
    for (int off=32;off>=1;off>>=1){
      a0 += __shfl_xor(a0,off);
      a1 += __shfl_xor(a1,off);
      a2 += __shfl_xor(a2,off);
    }
    if (lane==0 && j < nvalid){
      int node = sh_node[j];
      float bce = bcef(a0+b_topo[0], (float)is_parent[node])
                + bcef(a1+b_topo[1], (float)has_sib_lbl[node])
                + bcef(a2+b_topo[2], (float)is_res[node]);
      atomicAdd(loss_out, bce*INV_N);
    }
  }

  // label logits: all threads cooperate, NPB-way weight reuse
  for (int cb=0;cb<3;cb++){
    int c = cb*256 + t;
    if (c < VOCAB){
      float acc[NPB];
      #pragma unroll
      for (int j=0;j<NPB;j++) acc[j]=0.f;
      for (int k=0;k<LATENT;k++){
        float w = W_pred[k*VOCAB + c];
        #pragma unroll
        for (int j=0;j<NPB;j++) acc[j] += sh_pred[j][k]*w;
      }
      float b = b_pred[c];
      #pragma unroll
      for (int j=0;j<NPB;j++) sh_logits[j][c] = acc[j]+b;
    }
  }
  __syncthreads();

  // cross-entropy via log-softmax: wave wv handles node wv
  {
    int j = wv;
    float mx = -1e30f;
    for (int c=lane;c<VOCAB;c+=64) mx = fmaxf(mx, sh_logits[j][c]);
    #pragma unroll
    for (int off=32;off>=1;off>>=1) mx = fmaxf(mx, __shfl_xor(mx,off));
    float s = 0.f;
    for (int c=lane;c<VOCAB;c+=64) s += expf(sh_logits[j][c]-mx);
    #pragma unroll
    for (int off=32;off>=1;off>>=1) s += __shfl_xor(s,off);
    if (lane==0 && j < nvalid){
      float ce = logf(s) + mx - sh_logits[j][sh_feat[j]];
      atomicAdd(loss_out, ce*INV_N);
    }
  }

  // LSTM cell: gates = emb@W_ih^T + h_pu@W_hh^T + b ; order i,f,g,o
  {
    float gi[NPB],gf[NPB],gg[NPB],go[NPB];
    #pragma unroll
    for (int j=0;j<NPB;j++){ gi[j]=0.f;gf[j]=0.f;gg[j]=0.f;go[j]=0.f; }
    for (int k=0;k<EMBD;k++){
      const float* w = &W_ihT[k*GATES];
      float w0=w[t], w1=w[256+t], w2=w[512+t], w3=w[768+t];
      #pragma unroll
      for (int j=0;j<NPB;j++){
        float e = sh_emb[j][k];
        gi[j]+=e*w0; gf[j]+=e*w1; gg[j]+=e*w2; go[j]+=e*w3;
      }
    }
    for (int k=0;k<LATENT;k++){
      const float* w = &W_hhT[k*GATES];
      float w0=w[t], w1=w[256+t], w2=w[512+t], w3=w[768+t];
      #pragma unroll
      for (int j=0;j<NPB;j++){
        float h = sh_pu[j][k];
        gi[j]+=h*w0; gf[j]+=h*w1; gg[j]+=h*w2; go[j]+=h*w3;
      }
    }
    float bi  = b_ih[t]      + b_hh[t];
    float bf  = b_ih[256+t]  + b_hh[256+t];
    float bgg = b_ih[512+t]  + b_hh[512+t];
    float bo  = b_ih[768+t]  + b_hh[768+t];
    #pragma unroll
    for (int j=0;j<NPB;j++){
      int m = base + j;
      float c_old = c_state[sh_pidx[j]*LATENT + t];
      float i_ = sigm(gi[j]+bi);
      float f_ = sigm(gf[j]+bf);
      float g_ = tanhf(gg[j]+bgg);
      float o_ = sigm(go[j]+bo);
      float cn = f_*c_old + i_*g_;
      float hn = o_*tanhf(cn);
      tmp_h[m*LATENT+t] = hn;
      tmp_c[m*LATENT+t] = cn;
    }
  }
}

__global__ __launch_bounds__(LATENT) void scatter_kernel(int lvl,
    const int* __restrict__ lists, const int* __restrict__ counts,
    const float* __restrict__ tmp_h, const float* __restrict__ tmp_c,
    float* __restrict__ h_state, float* __restrict__ c_state)
{
  const int count = counts[lvl];
  const int base = blockIdx.x*NPB;
  if (base>=count) return;
  const int t = threadIdx.x;
  for (int j=0;j<NPB;j++){
    int m = base+j;
    if (m<count){
      int node = lists[lvl*NNODES+m];
      h_state[node*LATENT+t] = tmp_h[m*LATENT+t];
      c_state[node*LATENT+t] = tmp_c[m*LATENT+t];
    }
  }
}

extern "C" void kernel_launch(void* const* d_in, const int* in_sizes, int n_in,
                              void* d_out, int out_size, void* d_ws, size_t ws_size,
                              hipStream_t stream)
{
  const float* z         = (const float*)d_in[0];
  const float* emb_table = (const float*)d_in[1];
  const float* W_l2h     = (const float*)d_in[2];
  const float* b_l2h     = (const float*)d_in[3];
  const float* W_ih      = (const float*)d_in[4];
  const float* W_hh      = (const float*)d_in[5];
  const float* b_ih      = (const float*)d_in[6];
  const float* b_hh      = (const float*)d_in[7];
  const float* W_ph1     = (const float*)d_in[8];
  const float* b_ph1     = (const float*)d_in[9];
  const float* W_ph2     = (const float*)d_in[10];
  const float* b_ph2     = (const float*)d_in[11];
  const float* W_gate    = (const float*)d_in[12];
  const float* b_gate    = (const float*)d_in[13];
  const float* W_topo    = (const float*)d_in[14];
  const float* b_topo    = (const float*)d_in[15];
  const float* W_pred    = (const float*)d_in[16];
  const float* b_pred    = (const float*)d_in[17];
  const int* features    = (const int*)d_in[18];
  const int* node_level  = (const int*)d_in[19];
  const int* parent_idx  = (const int*)d_in[20];
  const int* sibling_idx = (const int*)d_in[21];
  const int* has_prev    = (const int*)d_in[22];
  const int* tree_id     = (const int*)d_in[23];
  const int* is_parent   = (const int*)d_in[24];
  const int* has_sib     = (const int*)d_in[25];
  const int* is_res      = (const int*)d_in[26];

  // workspace carve-out (~149 MB)
  char* ws = (char*)d_ws;
  size_t off = 0;
  auto alloc = [&](size_t bytes)->char*{
    char* p = ws + off; off += (bytes + 255) & ~(size_t)255; return p;
  };
  float* h_state = (float*)alloc((size_t)NNODES*LATENT*4);
  float* c_state = (float*)alloc((size_t)NNODES*LATENT*4);
  float* W_ihT   = (float*)alloc((size_t)EMBD*GATES*4);
  float* W_hhT   = (float*)alloc((size_t)LATENT*GATES*4);
  float* root_h  = (float*)alloc((size_t)NTREES*LATENT*4);
  float* tmp_h   = (float*)alloc((size_t)MAXM*LATENT*4);
  float* tmp_c   = (float*)alloc((size_t)MAXM*LATENT*4);
  int*   lists   = (int*)alloc((size_t)NLEV*NNODES*4);
  int*   counts  = (int*)alloc(64);
  float* loss    = (float*)d_out;

  zero_kernel<<<1,64,0,stream>>>(loss, counts);
  transpose_kernel<<<(GATES*EMBD+255)/256,256,0,stream>>>(W_ih, W_ihT, GATES, EMBD);
  transpose_kernel<<<(GATES*LATENT+255)/256,256,0,stream>>>(W_hh, W_hhT, GATES, LATENT);
  root_kernel<<<NTREES,LATENT,0,stream>>>(z, W_l2h, b_l2h, root_h);
  init_kernel<<<NNODES,LATENT,0,stream>>>(node_level, tree_id, root_h, h_state, c_state);
  build_lists_kernel<<<NNODES/256,256,0,stream>>>(node_level, counts, lists);

  for (int lvl=1; lvl<NLEV; lvl++){
    forward_kernel<<<MAXM/NPB,256,0,stream>>>(lvl, lists, counts, h_state, c_state,
        emb_table, features, parent_idx, sibling_idx, has_prev,
        is_parent, has_sib, is_res,
        W_ph1,b_ph1,W_ph2,b_ph2,W_gate,b_gate,W_topo,b_topo,W_pred,b_pred,
        W_ihT,W_hhT,b_ih,b_hh,tmp_h,tmp_c,loss);
    scatter_kernel<<<MAXM/NPB,256,0,stream>>>(lvl, lists, counts, tmp_h, tmp_c,
        h_state, c_state);
  }
}

// Round 2
// 1757.970 us; speedup vs baseline: 1.8717x; 1.8717x over previous
//
#include <hip/hip_runtime.h>
#include <math.h>

#define LATENT 256
#define EMBD 128
#define VOCAB 600
#define NLEV 12
#define NNODES 65536
#define NTREES 32
#define MAXM 6400            // >= count(+13 sigma); multiple of 128
#define INV_N (1.0f/65536.0f)

typedef unsigned short ushort_t;
typedef __attribute__((ext_vector_type(8))) short short8;
typedef __attribute__((ext_vector_type(4))) float float4v;

#define GLOBAL_AS __attribute__((address_space(1)))
#define LDS_AS __attribute__((address_space(3)))

__device__ __forceinline__ float sigm(float x){ return 1.0f/(1.0f+expf(-x)); }
__device__ __forceinline__ float bcef(float x, float y){
  return fmaxf(x,0.0f) - x*y + log1pf(expf(-fabsf(x)));
}
__device__ __forceinline__ ushort_t f2bf(float f){
  union{float f; unsigned u;} v; v.f=f;
  unsigned r = v.u + 0x7fffu + ((v.u>>16)&1u);
  return (ushort_t)(r>>16);
}
__device__ __forceinline__ float bf2f(ushort_t u){
  union{unsigned u; float f;} v; v.u = ((unsigned)u)<<16; return v.f;
}

__global__ void zero_kernel(float* loss, int* counts){
  int t = threadIdx.x;
  if (t==0) *loss = 0.0f;
  if (t<NLEV) counts[t]=0;
}

// Build bf16 weight layouts: all Bt matrices are [N_out][K] row-major.
__global__ void prep_kernel(const float* __restrict__ W_ph1, const float* __restrict__ W_ph2,
    const float* __restrict__ W_gate, const float* __restrict__ W_topo,
    const float* __restrict__ W_pred, const float* __restrict__ W_ih,
    const float* __restrict__ W_hh, const float* __restrict__ emb_table,
    ushort_t* __restrict__ W1t, ushort_t* __restrict__ W2t,
    ushort_t* __restrict__ W3t, ushort_t* __restrict__ embbf)
{
  int idx = blockIdx.x*256 + threadIdx.x;
  if (idx < 512*512){
    int o = idx >> 9, k = idx & 511;
    float v;
    if (o < 256) v = (k<256) ? W_ph1[k*256+o] : W_ph2[(k-256)*256+o];
    else         v = (k<256) ? 0.0f : W_gate[(k-256)*256+(o-256)];
    W1t[idx] = f2bf(v);
    return;
  }
  idx -= 512*512;
  if (idx < 640*256){
    int o = idx >> 8, k = idx & 255;
    float v = 0.0f;
    if (o < 3) v = W_topo[k*3+o];
    else if (o >= 8 && o < 608) v = W_pred[k*VOCAB + (o-8)];
    W2t[idx] = f2bf(v);
    return;
  }
  idx -= 640*256;
  if (idx < 1024*384){
    int o = idx / 384, k = idx - o*384;
    float v = (k<128) ? W_ih[o*128+k] : W_hh[o*256+(k-128)];
    W3t[idx] = f2bf(v);
    return;
  }
  idx -= 1024*384;
  if (idx < VOCAB*EMBD){
    embbf[idx] = f2bf(emb_table[idx]);
  }
}

__global__ __launch_bounds__(LATENT) void root_kernel(const float* __restrict__ z,
    const float* __restrict__ W, const float* __restrict__ b, float* __restrict__ root_h){
  __shared__ float zs[LATENT];
  int bi = blockIdx.x; int t = threadIdx.x;
  zs[t] = z[bi*LATENT+t];
  __syncthreads();
  float acc = b[t];
  for (int k=0;k<LATENT;k++) acc += zs[k]*W[t*LATENT+k];
  root_h[bi*LATENT+t] = acc;
}

__global__ __launch_bounds__(LATENT) void init_kernel(const int* __restrict__ node_level,
    const int* __restrict__ tree_id, const float* __restrict__ root_h,
    ushort_t* __restrict__ h_state, float* __restrict__ c_state){
  int t = threadIdx.x;
  for (int n = blockIdx.x; n < NNODES; n += gridDim.x){
    int lvl = node_level[n];
    ushort_t h = 0;
    if (lvl==0) h = f2bf(root_h[tree_id[n]*LATENT + t]);
    h_state[(size_t)n*LATENT+t]=h;
    c_state[(size_t)n*LATENT+t]=0.0f;
  }
}

__global__ void build_lists_kernel(const int* __restrict__ node_level,
    int* __restrict__ counts, int* __restrict__ lists){
  int n = blockIdx.x*blockDim.x + threadIdx.x;
  if (n>=NNODES) return;
  int lvl = node_level[n];
  if (lvl>=1){
    int pos = atomicAdd(&counts[lvl],1);
    if (pos < MAXM) lists[lvl*MAXM + pos] = n;
  }
}

// X1[m] = [h_par bf16 | h_sib bf16]; X3[m][0:128] = emb bf16; Cpar[m] = c_par fp32
__global__ __launch_bounds__(LATENT) void gather_kernel(
    int lvl, const int* __restrict__ lists, const int* __restrict__ counts,
    const ushort_t* __restrict__ h_state, const float* __restrict__ c_state,
    const ushort_t* __restrict__ embbf, const int* __restrict__ features,
    const int* __restrict__ parent_idx, const int* __restrict__ sibling_idx,
    const int* __restrict__ has_prev,
    ushort_t* __restrict__ X1, ushort_t* __restrict__ X3, float* __restrict__ Cpar)
{
  const int count = min(counts[lvl], MAXM);
  const int Mt = (count + 127) & ~127;
  const int t = threadIdx.x;
  for (int m = blockIdx.x; m < Mt; m += gridDim.x){
    if (m < count){
      int node = lists[lvl*MAXM + m];
      int pi = parent_idx[node];
      ushort_t hp = h_state[(size_t)pi*LATENT + t];
      ushort_t hs = 0;
      if (has_prev[node] > 0) hs = h_state[(size_t)sibling_idx[node]*LATENT + t];
      X1[(size_t)m*512 + t] = hp;
      X1[(size_t)m*512 + 256 + t] = hs;
      Cpar[(size_t)m*LATENT + t] = c_state[(size_t)pi*LATENT + t];
      if (t < EMBD) X3[(size_t)m*384 + t] = embbf[features[node]*EMBD + t];
    } else {
      X1[(size_t)m*512 + t] = 0;
      X1[(size_t)m*512 + 256 + t] = 0;
      Cpar[(size_t)m*LATENT + t] = 0.0f;
      if (t < EMBD) X3[(size_t)m*384 + t] = 0;
    }
  }
}

// C[M,N] f32 = A[M,K] bf16 row-major  x  Bt[N,K] bf16 row-major (B transposed)
// m97 structure: 128x128x64 tile, 4 waves, global_load_lds(16B), T2 XOR swizzle.
__global__ __launch_bounds__(256) void gemm_kernel(
    const ushort_t* __restrict__ A, int lda,
    const ushort_t* __restrict__ Bt,
    float* __restrict__ C, int N, int K,
    const int* __restrict__ counts, int lvl)
{
  const int count = min(counts[lvl], MAXM);
  const int m0 = blockIdx.x * 128;
  if (m0 >= count) return;
  const int n0 = blockIdx.y * 128;

  __shared__ ushort_t As[128*64];
  __shared__ ushort_t Bs[128*64];

  const int t = threadIdx.x;
  const int lane = t & 63;
  const int wv = t >> 6;
  const int wr = wv >> 1, wc = wv & 1;

  // staging geometry: thread covers (row = t>>3 + 32*i, 16B at kb=(t&7)*16)
  const int srow = t >> 3;
  const int skb  = (t & 7) * 16;

  float4v acc[4][4];
  #pragma unroll
  for (int i=0;i<4;i++){
    #pragma unroll
    for (int j=0;j<4;j++){ acc[i][j] = (float4v){0.f,0.f,0.f,0.f}; }
  }

  const char* Ab = (const char*)A;
  const char* Bb = (const char*)Bt;
  char* AsB = (char*)As;
  char* BsB = (char*)Bs;

  for (int k0 = 0; k0 < K; k0 += 64){
    #pragma unroll
    for (int i=0;i<4;i++){
      int row = srow + 32*i;
      int kbs = skb ^ ((row & 7) << 4);           // inverse-swizzled SOURCE
      const void* gsrc = Ab + ((size_t)(m0+row)*lda + k0)*2 + kbs;
      void* ldst = AsB + (i*4096 + wv*1024 + lane*16);  // linear DEST
      __builtin_amdgcn_global_load_lds((const GLOBAL_AS void*)gsrc,
          (LDS_AS void*)ldst, 16, 0, 0);
    }
    #pragma unroll
    for (int i=0;i<4;i++){
      int row = srow + 32*i;
      int kbs = skb ^ ((row & 7) << 4);
      const void* gsrc = Bb + ((size_t)(n0+row)*K + k0)*2 + kbs;
      void* ldst = BsB + (i*4096 + wv*1024 + lane*16);
      __builtin_amdgcn_global_load_lds((const GLOBAL_AS void*)gsrc,
          (LDS_AS void*)ldst, 16, 0, 0);
    }
    __syncthreads();

    #pragma unroll
    for (int kk=0;kk<2;kk++){
      short8 af[4], bfr[4];
      const int kb = kk*64 + (lane>>4)*16;
      #pragma unroll
      for (int mf=0;mf<4;mf++){
        int row = wr*64 + mf*16 + (lane&15);
        af[mf] = *(const short8*)(AsB + row*128 + (kb ^ ((row&7)<<4)));  // swizzled READ
      }
      #pragma unroll
      for (int nf=0;nf<4;nf++){
        int row = wc*64 + nf*16 + (lane&15);
        bfr[nf] = *(const short8*)(BsB + row*128 + (kb ^ ((row&7)<<4)));
      }
      #pragma unroll
      for (int mf=0;mf<4;mf++){
        #pragma unroll
        for (int nf=0;nf<4;nf++){
          acc[mf][nf] = __builtin_amdgcn_mfma_f32_16x16x32_bf16(af[mf], bfr[nf], acc[mf][nf], 0,0,0);
        }
      }
    }
    __syncthreads();
  }

  // epilogue: D col=lane&15, row=(lane>>4)*4+reg  [m89-verified]
  #pragma unroll
  for (int mf=0;mf<4;mf++){
    int rbase = m0 + wr*64 + mf*16 + (lane>>4)*4;
    #pragma unroll
    for (int nf=0;nf<4;nf++){
      int col = n0 + wc*64 + nf*16 + (lane&15);
      #pragma unroll
      for (int r=0;r<4;r++){
        C[(size_t)(rbase+r)*N + col] = acc[mf][nf][r];
      }
    }
  }
}

// h_pred = tanh(C1[:,0:256]+bph); pu = hp + sigm(C1[:,256:512]+bg)*hs
__global__ __launch_bounds__(LATENT) void mid_kernel(
    const int* __restrict__ counts, int lvl, const float* __restrict__ C1,
    const ushort_t* __restrict__ X1,
    const float* __restrict__ b_ph1, const float* __restrict__ b_ph2,
    const float* __restrict__ b_gate,
    ushort_t* __restrict__ A2, ushort_t* __restrict__ X3)
{
  const int count = min(counts[lvl], MAXM);
  const int Mt = (count+127)&~127;
  const int t = threadIdx.x;
  const float bp = b_ph1[t] + b_ph2[t];
  const float bg = b_gate[t];
  for (int m = blockIdx.x; m < Mt; m += gridDim.x){
    if (m < count){
      float pre  = C1[(size_t)m*512 + t] + bp;
      float gpre = C1[(size_t)m*512 + 256 + t] + bg;
      float hp = bf2f(X1[(size_t)m*512 + t]);
      float hs = bf2f(X1[(size_t)m*512 + 256 + t]);
      A2[(size_t)m*LATENT + t] = f2bf(tanhf(pre));
      X3[(size_t)m*384 + 128 + t] = f2bf(hp + sigm(gpre)*hs);
    } else {
      A2[(size_t)m*LATENT + t] = 0;
      X3[(size_t)m*384 + 128 + t] = 0;
    }
  }
}

// BCE from C2[:,0:3]+b_topo, CE from C2[:,8:608]+b_pred. One wave per node.
__global__ __launch_bounds__(256) void loss_kernel(
    const int* __restrict__ counts, int lvl, const int* __restrict__ lists,
    const float* __restrict__ C2, const float* __restrict__ b_topo,
    const float* __restrict__ b_pred,
    const int* __restrict__ features, const int* __restrict__ is_parent,
    const int* __restrict__ has_sib, const int* __restrict__ is_res,
    float* __restrict__ loss)
{
  const int count = min(counts[lvl], MAXM);
  const int lane = threadIdx.x & 63;
  const int wv = threadIdx.x >> 6;
  for (int m = blockIdx.x*4 + wv; m < count; m += gridDim.x*4){
    const float* row = C2 + (size_t)m*640;
    int node = lists[lvl*MAXM + m];
    int feat = features[node];
    float mx = -1e30f, lf = 0.0f;
    float vals[10];
    #pragma unroll
    for (int i=0;i<10;i++){
      int c = lane + i*64;
      float v = (c < VOCAB) ? (row[8+c] + b_pred[c]) : -1e30f;
      vals[i] = v;
      mx = fmaxf(mx, v);
      if (c == feat) lf = v;
    }
    #pragma unroll
    for (int off=32;off>=1;off>>=1) mx = fmaxf(mx, __shfl_xor(mx, off));
    float s = 0.0f;
    #pragma unroll
    for (int i=0;i<10;i++) s += expf(vals[i]-mx);
    #pragma unroll
    for (int off=32;off>=1;off>>=1) s += __shfl_xor(s, off);
    #pragma unroll
    for (int off=32;off>=1;off>>=1) lf += __shfl_xor(lf, off);
    if (lane == 0){
      float ce = logf(s) + mx - lf;
      float bce = bcef(row[0]+b_topo[0], (float)is_parent[node])
                + bcef(row[1]+b_topo[1], (float)has_sib[node])
                + bcef(row[2]+b_topo[2], (float)is_res[node]);
      atomicAdd(loss, (ce + bce) * INV_N);
    }
  }
}

// gates i,f,g,o at C3 cols t, 256+t, 512+t, 768+t; scatter h(bf16)/c(f32)
__global__ __launch_bounds__(LATENT) void lstm_kernel(
    const int* __restrict__ counts, int lvl, const int* __restrict__ lists,
    const float* __restrict__ C3, const float* __restrict__ Cpar,
    const float* __restrict__ b_ih, const float* __restrict__ b_hh,
    ushort_t* __restrict__ h_state, float* __restrict__ c_state)
{
  const int count = min(counts[lvl], MAXM);
  const int t = threadIdx.x;
  const float bi = b_ih[t]       + b_hh[t];
  const float bff= b_ih[256+t]   + b_hh[256+t];
  const float bg = b_ih[512+t]   + b_hh[512+t];
  const float bo = b_ih[768+t]   + b_hh[768+t];
  for (int m = blockIdx.x; m < count; m += gridDim.x){
    int node = lists[lvl*MAXM + m];
    const float* g = C3 + (size_t)m*1024;
    float i_ = sigm(g[t] + bi);
    float f_ = sigm(g[256+t] + bff);
    float gg = tanhf(g[512+t] + bg);
    float o_ = sigm(g[768+t] + bo);
    float cn = f_*Cpar[(size_t)m*LATENT+t] + i_*gg;
    h_state[(size_t)node*LATENT+t] = f2bf(o_*tanhf(cn));
    c_state[(size_t)node*LATENT+t] = cn;
  }
}

extern "C" void kernel_launch(void* const* d_in, const int* in_sizes, int n_in,
                              void* d_out, int out_size, void* d_ws, size_t ws_size,
                              hipStream_t stream)
{
  const float* z         = (const float*)d_in[0];
  const float* emb_table = (const float*)d_in[1];
  const float* W_l2h     = (const float*)d_in[2];
  const float* b_l2h     = (const float*)d_in[3];
  const float* W_ih      = (const float*)d_in[4];
  const float* W_hh      = (const float*)d_in[5];
  const float* b_ih      = (const float*)d_in[6];
  const float* b_hh      = (const float*)d_in[7];
  const float* W_ph1     = (const float*)d_in[8];
  const float* b_ph1     = (const float*)d_in[9];
  const float* W_ph2     = (const float*)d_in[10];
  const float* b_ph2     = (const float*)d_in[11];
  const float* W_gate    = (const float*)d_in[12];
  const float* b_gate    = (const float*)d_in[13];
  const float* W_topo    = (const float*)d_in[14];
  const float* b_topo    = (const float*)d_in[15];
  const float* W_pred    = (const float*)d_in[16];
  const float* b_pred    = (const float*)d_in[17];
  const int* features    = (const int*)d_in[18];
  const int* node_level  = (const int*)d_in[19];
  const int* parent_idx  = (const int*)d_in[20];
  const int* sibling_idx = (const int*)d_in[21];
  const int* has_prev    = (const int*)d_in[22];
  const int* tree_id     = (const int*)d_in[23];
  const int* is_parent   = (const int*)d_in[24];
  const int* has_sib     = (const int*)d_in[25];
  const int* is_res      = (const int*)d_in[26];

  char* ws = (char*)d_ws;
  size_t off = 0;
  auto alloc = [&](size_t bytes)->char*{
    char* p = ws + off; off += (bytes + 255) & ~(size_t)255; return p;
  };
  ushort_t* h_state = (ushort_t*)alloc((size_t)NNODES*LATENT*2);   // 32 MB (bf16)
  float*    c_state = (float*)alloc((size_t)NNODES*LATENT*4);      // 64 MB
  ushort_t* X1      = (ushort_t*)alloc((size_t)MAXM*512*2);        // 6.25 MB
  ushort_t* A2      = (ushort_t*)alloc((size_t)MAXM*LATENT*2);     // 3.1 MB
  ushort_t* X3      = (ushort_t*)alloc((size_t)MAXM*384*2);        // 4.7 MB
  float*    Cbig    = (float*)alloc((size_t)MAXM*1024*4);          // 25 MB (C1/C2/C3 time-shared)
  float*    Cpar    = (float*)alloc((size_t)MAXM*LATENT*4);        // 6.25 MB
  ushort_t* W1t     = (ushort_t*)alloc((size_t)512*512*2);
  ushort_t* W2t     = (ushort_t*)alloc((size_t)640*256*2);
  ushort_t* W3t     = (ushort_t*)alloc((size_t)1024*384*2);
  ushort_t* embbf   = (ushort_t*)alloc((size_t)VOCAB*EMBD*2);
  float*    root_h  = (float*)alloc((size_t)NTREES*LATENT*4);
  int*      lists   = (int*)alloc((size_t)NLEV*MAXM*4);
  int*      counts  = (int*)alloc(64);
  float*    loss    = (float*)d_out;

  float* C1 = Cbig;  // [MAXM][512]
  float* C2 = Cbig;  // [MAXM][640]  (C1 dead by then)
  float* C3 = Cbig;  // [MAXM][1024] (C2 dead by then)

  zero_kernel<<<1,64,0,stream>>>(loss, counts);
  prep_kernel<<<3500,256,0,stream>>>(W_ph1,W_ph2,W_gate,W_topo,W_pred,W_ih,W_hh,emb_table,
                                     W1t,W2t,W3t,embbf);
  root_kernel<<<NTREES,LATENT,0,stream>>>(z, W_l2h, b_l2h, root_h);
  init_kernel<<<2048,LATENT,0,stream>>>(node_level, tree_id, root_h, h_state, c_state);
  build_lists_kernel<<<NNODES/256,256,0,stream>>>(node_level, counts, lists);

  for (int lvl=1; lvl<NLEV; lvl++){
    gather_kernel<<<1024,LATENT,0,stream>>>(lvl, lists, counts, h_state, c_state,
        embbf, features, parent_idx, sibling_idx, has_prev, X1, X3, Cpar);
    gemm_kernel<<<dim3(MAXM/128,4),256,0,stream>>>(X1, 512, W1t, C1, 512, 512, counts, lvl);
    mid_kernel<<<1024,LATENT,0,stream>>>(counts, lvl, C1, X1, b_ph1, b_ph2, b_gate, A2, X3);
    gemm_kernel<<<dim3(MAXM/128,5),256,0,stream>>>(A2, 256, W2t, C2, 640, 256, counts, lvl);
    loss_kernel<<<512,256,0,stream>>>(counts, lvl, lists, C2, b_topo, b_pred,
        features, is_parent, has_sib, is_res, loss);
    gemm_kernel<<<dim3(MAXM/128,8),256,0,stream>>>(X3, 384, W3t, C3, 1024, 384, counts, lvl);
    lstm_kernel<<<1024,LATENT,0,stream>>>(counts, lvl, lists, C3, Cpar,
        b_ih, b_hh, h_state, c_state);
  }
}